// Round 1
// 92.231 us; speedup vs baseline: 1.0425x; 1.0425x over previous
//
#include <hip/hip_runtime.h>
#include <string.h>

#define NCRD 4096
#define NROW 8192
#define MT   32            // rows per block -> 256 blocks (1/CU)
#define WG_U4 94208        // total prepped weight size in uint4 (1.44 MB)

typedef __attribute__((ext_vector_type(8))) _Float16 half8;
typedef __attribute__((ext_vector_type(4))) float f32x4;
typedef __attribute__((ext_vector_type(4))) int   i32x4;

static __device__ __forceinline__ float sinrev(float t){ return __builtin_amdgcn_sinf(__builtin_amdgcn_fractf(t)); }
static __device__ __forceinline__ float cosrev(float t){ return __builtin_amdgcn_cosf(__builtin_amdgcn_fractf(t)); }
static __device__ __forceinline__ unsigned short f2h(float f){   // RNE f32->fp16
    _Float16 h = (_Float16)f;
    unsigned short u; memcpy(&u, &h, 2); return u;
}

// Scheduler-opaque 16B global load: cannot be sunk/reordered by the compiler.
static __device__ __forceinline__ i32x4 gload16(const uint4* p){
    i32x4 r;
    asm volatile("global_load_dwordx4 %0, %1, off" : "=v"(r) : "v"(p) : "memory");
    return r;
}
// Explicit vmcnt gate, data-tied to the reg about to be consumed.
// K folds to a constant under full unroll.
static __device__ __forceinline__ void vmwaitK(int K, i32x4& a){
    if (K >= 8)      asm volatile("s_waitcnt vmcnt(8)" : "+v"(a));
    else if (K == 7) asm volatile("s_waitcnt vmcnt(7)" : "+v"(a));
    else if (K == 6) asm volatile("s_waitcnt vmcnt(6)" : "+v"(a));
    else if (K == 5) asm volatile("s_waitcnt vmcnt(5)" : "+v"(a));
    else if (K == 4) asm volatile("s_waitcnt vmcnt(4)" : "+v"(a));
    else if (K == 3) asm volatile("s_waitcnt vmcnt(3)" : "+v"(a));
    else if (K == 2) asm volatile("s_waitcnt vmcnt(2)" : "+v"(a));
    else if (K == 1) asm volatile("s_waitcnt vmcnt(1)" : "+v"(a));
    else             asm volatile("s_waitcnt vmcnt(0)" : "+v"(a));
}

// LDS-only barrier: drains lgkmcnt (ds ops) but NOT vmcnt, so the next
// layer's weight-prologue loads stay in flight across the barrier.
// (__syncthreads would emit s_waitcnt vmcnt(0) lgkmcnt(0) and kill the
// 8-deep pipeline at every layer entry.) sched_barrier fences per rule #18.
static __device__ __forceinline__ void xbar(){
    __builtin_amdgcn_sched_barrier(0);
    asm volatile("s_waitcnt lgkmcnt(0)" ::: "memory");
    __builtin_amdgcn_s_barrier();
    __builtin_amdgcn_sched_barrier(0);
}

// Weight layout per layer (uint4 idx = c*1024 + w*64 + lane, lane=lq*16+lr):
//  fp16 chunks c<8 : B[k=c*32+lq*8+j][col=w*16+lr], j=0..7  (linear term, or gemm W/2pi)
//  i8  chunks c>=8 : B[k=(c-8)*64+lq*16+j][col=w*16+lr], j=0..15
//                    value = rint(-w^3/6 * 6350), abs-quantized (|w^3/6| <= 0.02)
// Sin layers: 12288 u4 (8 fp16 + 4 i8 chunks, K=256 each term).
// Gemm layers: 8192 u4 (8 fp16 chunks).
__constant__ int c_offs[9] = {0,12288,20480,32768,40960,53248,61440,73728,81920};

// ---- prep: one coalesced uint4 store per thread; l==9: bias+coords --------
__global__ void prep_kernel(const float* __restrict__ w0, const float* __restrict__ ws,
                            const float* __restrict__ wlast, const float* __restrict__ w1,
                            const float* __restrict__ coords, const float* __restrict__ b1,
                            uint4* __restrict__ Wg, float* __restrict__ b1s,
                            float* __restrict__ out)
{
    int l = blockIdx.x, part = blockIdx.y, t = threadIdx.x;
    const float inv2pi = 0.15915494309189535f;
    if (l == 9) {
        int base = part*256 + t;                       // 0..12287
        if (base < 1024) b1s[base] = b1[base]*inv2pi;
        for (int i = base; i < NCRD*6; i += 12288)
            out[(size_t)NROW*256 + i] = coords[i];
        return;
    }
    bool sinl = !(l & 1);
    if (!sinl && part >= 32) return;                   // gemm layers: 8192 uint4
    const float* src;
    switch (l) {
        case 0: src = w0;          break;
        case 1: src = w1;          break;
        case 2: src = ws;          break;
        case 3: src = w1+65536;    break;
        case 4: src = ws+65536;    break;
        case 5: src = w1+2*65536;  break;
        case 6: src = ws+2*65536;  break;
        case 7: src = w1+3*65536;  break;
        default: src = wlast;      break;
    }
    int idx = part*256 + t;                 // uint4 index within layer
    int c  = idx >> 10, rem = idx & 1023;
    int w  = rem >> 6, lane = rem & 63;
    int lq = lane >> 4, lr = lane & 15;
    int col = w*16 + lr;
    if (sinl && c >= 8) {                   // cubic term, int8
        int k0 = (c-8)*64 + lq*16;
        const float* s = src + col*256 + k0;
        signed char n[16];
        #pragma unroll
        for (int j = 0; j < 16; ++j) {
            float wv = s[j];
            float cub = -wv*wv*wv*(1.0f/6.0f);
            float q = rintf(cub*6350.0f);   // CMAX = 127/6350 = 0.02
            q = fminf(127.0f, fmaxf(-127.0f, q));
            n[j] = (signed char)(int)q;
        }
        uint4 o; memcpy(&o, n, 16);
        Wg[c_offs[l] + idx] = o;
    } else {                                // linear / gemm term, fp16
        int k0 = c*32 + lq*8;
        const float* s = src + col*256 + k0;
        unsigned short h[8];
        #pragma unroll
        for (int j = 0; j < 8; ++j) {
            float wv = s[j];
            h[j] = f2h(sinl ? wv : wv*inv2pi);
        }
        uint4 o; memcpy(&o, h, 16);
        Wg[c_offs[l] + idx] = o;            // coalesced 16B store
    }
}

// A-fragment fetch: fp16 frags from xa (16 KB), i8 x^3 frags from xc (8 KB).
// c is compile-time under full unroll -> address const-folds.
#define AFRAG(xaf, xcf, c, half) \
    ((c) < NCF ? (xaf)[((c)*4+lq)*32 + (half)*16 + lr] \
               : (xcf)[(((c)-NCF)*4+lq)*32 + (half)*16 + lr])

// ---------------- one layer: 16 waves, 1 load/chunk/wave -------------------
// MODE: 0 = sin-layer (identity fp16 write), 1 = gemm (sin + fp16 + i8 cube),
//       2 = last sin layer (fp32 global write).
// NCF fp16 chunks (f16 MFMA, K=32 each) then NCC i8 chunks (i8 MFMA, K=64).
template<int MODE, int NCF, int NCC>
static __device__ __forceinline__ void do_layer(
    const uint4* __restrict__ wq,     // per-wave/lane weight base for this layer
    const float* __restrict__ br,     // bias row base (MODE 1)
    float* __restrict__ outg,         // global out (MODE 2)
    unsigned short* xa, signed char* xc,
    int wv, int lq, int lr, int n0)
{
    constexpr int NC = NCF + NCC;
    constexpr int PD = 8;             // chunks in flight per wave (8 x 1KB)
    constexpr int RS = PD + 1;        // ring slots: consume slot != issue slot
    constexpr int PA = 2;             // A-fragment (LDS) prefetch depth
    f32x4 accL0 = {0.f,0.f,0.f,0.f}, accL1 = accL0;
    i32x4 accC0 = {0,0,0,0},          accC1 = accC0;

    i32x4 ring[RS];
    #pragma unroll
    for (int p = 0; p < PD; ++p)      // prologue: stays in flight across xbar
        if (p < NC) ring[p % RS] = gload16(wq + p*1024);

    xbar();                           // prior xa/xc writes visible (lgkm only)

    const i32x4* xaf = (const i32x4*)xa;
    const i32x4* xcf = (const i32x4*)xc;
    i32x4 pa0[PA], pa1[PA];
    #pragma unroll
    for (int p = 0; p < PA; ++p) {
        pa0[p] = AFRAG(xaf, xcf, p, 0);
        pa1[p] = AFRAG(xaf, xcf, p, 1);
    }
    #pragma unroll
    for (int c = 0; c < NC; ++c) {
        if (c + PD < NC)              // issue into slot consumed PD iters ago
            ring[(c+PD) % RS] = gload16(wq + (c+PD)*1024);
        int K = NC-1-c;
        vmwaitK(K > PD ? PD : K, ring[c % RS]);
        i32x4 b  = ring[c % RS];
        i32x4 a0 = pa0[c % PA], a1 = pa1[c % PA];
        if (c + PA < NC) {
            pa0[c % PA] = AFRAG(xaf, xcf, c+PA, 0);
            pa1[c % PA] = AFRAG(xaf, xcf, c+PA, 1);
        }
        if (c < NCF) {
            half8 bh, ah0, ah1;
            memcpy(&bh, &b, 16); memcpy(&ah0, &a0, 16); memcpy(&ah1, &a1, 16);
            accL0 = __builtin_amdgcn_mfma_f32_16x16x32_f16(ah0, bh, accL0, 0,0,0);
            accL1 = __builtin_amdgcn_mfma_f32_16x16x32_f16(ah1, bh, accL1, 0,0,0);
        } else {
            accC0 = __builtin_amdgcn_mfma_i32_16x16x64_i8(a0, b, accC0, 0,0,0);
            accC1 = __builtin_amdgcn_mfma_i32_16x16x64_i8(a1, b, accC1, 0,0,0);
        }
    }
    xbar();                           // all xa/xc reads done
    // ---- epilogue (bias loaded here: keeps K-loop vmcnt exclusively ours) --
    float bb = 0.f;
    if constexpr (MODE == 1) bb = br[wv*16 + lr];
    const float sC = 1.0f/806450.0f;  // 1/(127*6350): i8 cube rescale
    int h = wv*16 + lr;
    #pragma unroll
    for (int rt = 0; rt < 2; ++rt) {
        f32x4 A = rt==0 ? accL0 : accL1;
        i32x4 C = rt==0 ? accC0 : accC1;
        #pragma unroll
        for (int r = 0; r < 4; ++r) {
            float v = A[r];
            if constexpr (NCC > 0) v += (float)C[r] * sC;
            int m = rt*16 + lq*4 + r;       // C row = quad*4 + reg (m89)
            if constexpr (MODE == 2) {
                outg[(size_t)(n0 + m)*256 + h] = v;
            } else if constexpr (MODE == 1) {
                float s = sinrev(v + bb);   // weights pre-scaled 1/2pi
                xa[((h>>3)*32 + m)*8 + (h&7)] = f2h(s);
                float q = rintf(s*s*s*127.0f);
                q = fminf(127.0f, fmaxf(-127.0f, q));
                xc[((h>>4)*32 + m)*16 + (h&15)] = (signed char)(int)q;
            } else {
                xa[((h>>3)*32 + m)*8 + (h&7)] = f2h(v);
            }
        }
    }
}

// ---------------- fused MFMA network kernel --------------------------------
// 1024 threads = 16 waves/CU = 4 waves/SIMD: TLP to absorb L2 latency slop.
// __launch_bounds__(1024, 4) caps VGPR at 128.
__global__ __launch_bounds__(1024, 4)
void net_kernel(const float* __restrict__ coords, const float* __restrict__ Bm,
                const uint4* __restrict__ Wg, const float* __restrict__ b1s,
                float* __restrict__ out)
{
    __shared__ __align__(16) unsigned short xa[32*32*8];  // 16KB fp16 acts [kb8][m][k%8]
    __shared__ __align__(16) signed char    xc[16*32*16]; //  8KB i8 x^3   [kb16][m][k%16]
    __shared__ float cb[MT*3];
    __shared__ float bl[384];

    int tid = threadIdx.x, lane = tid & 63, wv = tid >> 6;   // wv 0..15
    int lq = lane >> 4, lr = lane & 15;
    int n0 = blockIdx.x * MT;

    // ---- fourier features (fp16) + x^3 (i8) -> xa/xc ----
    if (tid < MT*3) {
        int r = tid/3, d = tid - 3*r, nv = n0 + r;
        cb[tid] = (nv < NCRD) ? coords[nv*6 + d] : coords[(nv-NCRD)*6 + 3 + d];
    }
    if (tid < 384) bl[tid] = Bm[tid];
    __syncthreads();
    {
        int m = tid & 31, cg = tid >> 5;        // col-group 0..31, 8 cols each
        float c0 = cb[m*3], c1 = cb[m*3+1], c2 = cb[m*3+2];
        unsigned short tx[8]; signed char tq[8];
        #pragma unroll
        for (int j = 0; j < 8; ++j) {
            int col = cg*8 + j, f = col & 127;
            float p = c0*bl[f] + c1*bl[128+f] + c2*bl[256+f];   // 2pi cancels
            float s = (col < 128) ? sinrev(p) : cosrev(p);
            tx[j] = f2h(s);
            float q = rintf(s*s*s*127.0f);
            q = fminf(127.0f, fmaxf(-127.0f, q));
            tq[j] = (signed char)(int)q;
        }
        uint4 vx; memcpy(&vx, tx, 16);
        *(uint4*)&xa[(cg*32 + m)*8] = vx;
        unsigned long long vq; memcpy(&vq, tq, 8);
        *(unsigned long long*)&xc[((cg>>1)*32 + m)*16 + (cg&1)*8] = vq;
    }
    // (each do_layer's entry xbar orders xa/xc writes before reads)

    int wl = wv*64 + lane;
    do_layer<0,8,4>(Wg +     0 + wl, nullptr,   nullptr, xa, xc, wv, lq, lr, n0);
    do_layer<1,8,0>(Wg + 12288 + wl, b1s + 0,   nullptr, xa, xc, wv, lq, lr, n0);
    do_layer<0,8,4>(Wg + 20480 + wl, nullptr,   nullptr, xa, xc, wv, lq, lr, n0);
    do_layer<1,8,0>(Wg + 32768 + wl, b1s + 256, nullptr, xa, xc, wv, lq, lr, n0);
    do_layer<0,8,4>(Wg + 40960 + wl, nullptr,   nullptr, xa, xc, wv, lq, lr, n0);
    do_layer<1,8,0>(Wg + 53248 + wl, b1s + 512, nullptr, xa, xc, wv, lq, lr, n0);
    do_layer<0,8,4>(Wg + 61440 + wl, nullptr,   nullptr, xa, xc, wv, lq, lr, n0);
    do_layer<1,8,0>(Wg + 73728 + wl, b1s + 768, nullptr, xa, xc, wv, lq, lr, n0);
    do_layer<2,8,4>(Wg + 81920 + wl, nullptr,   out,     xa, xc, wv, lq, lr, n0);
}

// ---------------- launch ---------------------------------------------------
extern "C" void kernel_launch(void* const* d_in, const int* in_sizes, int n_in,
                              void* d_out, int out_size, void* d_ws, size_t ws_size,
                              hipStream_t stream)
{
    const float* coords = (const float*)d_in[0];
    const float* Bm     = (const float*)d_in[1];
    const float* w0     = (const float*)d_in[2];
    const float* ws     = (const float*)d_in[3];
    const float* wlast  = (const float*)d_in[4];
    const float* w1     = (const float*)d_in[5];
    const float* b1     = (const float*)d_in[6];
    float* out = (float*)d_out;

    uint4* Wg  = (uint4*)d_ws;                                   // 1.44 MB
    float* b1s = (float*)((char*)d_ws + (size_t)WG_U4*16);       // 4 KB fp32

    dim3 pg(10, 48);
    prep_kernel<<<pg, 256, 0, stream>>>(w0, ws, wlast, w1, coords, b1, Wg, b1s, out);
    net_kernel<<<NROW/MT, 1024, 0, stream>>>(coords, Bm, Wg, b1s, out);
}